// Round 7
// baseline (394.502 us; speedup 1.0000x reference)
//
#include <hip/hip_runtime.h>
#include <stdint.h>

typedef __bf16 bf16x8 __attribute__((ext_vector_type(8)));
typedef float f32x4 __attribute__((ext_vector_type(4)));
typedef unsigned short u16;

__device__ __forceinline__ u16 f2bf(float f){
  uint32_t u = __float_as_uint(f);
  u = (u + 0x7fffu + ((u >> 16) & 1u)) >> 16;
  return (u16)u;
}
__device__ __forceinline__ float bf2f(u16 v){
  return __uint_as_float(((uint32_t)v) << 16);
}
__device__ __forceinline__ void gl_lds16(const void* g, void* l){
  __builtin_amdgcn_global_load_lds((const __attribute__((address_space(1))) void*)g,
                                   (__attribute__((address_space(3))) void*)l, 16, 0, 0);
}

// ---------------------------------------------------------------------------
// Weight prep: w1/w3 cvt, w2 repack [O][kq][C]
// ---------------------------------------------------------------------------
__global__ __launch_bounds__(256) void prep_w(
    const float* __restrict__ w1, const float* __restrict__ w2,
    const float* __restrict__ w3, u16* __restrict__ wb1, u16* __restrict__ wb2,
    u16* __restrict__ wb3){
  int bid = blockIdx.x, t = threadIdx.x;
  if (bid < 1024){
    int i = bid*256 + t; wb1[i] = f2bf(w1[i]);
  } else if (bid < 3328){
    int i = (bid-1024)*256 + t;
    int o = i / 2304, r = i - o*2304, kq = r >> 8, c = r & 255;
    wb2[i] = f2bf(w2[((size_t)o*256 + c)*9 + kq]);
  } else {
    int i = (bid-3328)*256 + t; wb3[i] = f2bf(w3[i]);
  }
}

// ---------------------------------------------------------------------------
// x [128][1024][196] f32 NCHW -> xp0 [b*196+p][1024] bf16
// ---------------------------------------------------------------------------
__global__ __launch_bounds__(256) void transform_x(const float* __restrict__ x,
                                                   u16* __restrict__ xp0){
  __shared__ float lds[64*201];
  const int b = blockIdx.y, c0 = blockIdx.x*64, t = threadIdx.x;
  const float4* src = (const float4*)x + (size_t)b*50176 + (size_t)c0*49;
  #pragma unroll
  for (int r = 0; r < 13; ++r){
    int q = r*256 + t;
    if (q < 3136){
      unsigned c = (unsigned)q / 49u, f = (unsigned)q - c*49u;
      float4 v = src[q];
      float* d = &lds[c*201 + f*4];
      d[0]=v.x; d[1]=v.y; d[2]=v.z; d[3]=v.w;
    }
  }
  __syncthreads();
  const int c4 = (t & 15)*4, pg = t >> 4;
  #pragma unroll
  for (int r = 0; r < 13; ++r){
    int p = r*16 + pg;
    if (p < 196){
      ushort4 pk;
      ((u16*)&pk)[0] = f2bf(lds[(c4+0)*201 + p]);
      ((u16*)&pk)[1] = f2bf(lds[(c4+1)*201 + p]);
      ((u16*)&pk)[2] = f2bf(lds[(c4+2)*201 + p]);
      ((u16*)&pk)[3] = f2bf(lds[(c4+3)*201 + p]);
      *(ushort4*)&xp0[((size_t)b*196 + p)*1024 + c0 + c4] = pk;
    }
  }
}

// ---------------------------------------------------------------------------
// FUSED conv1 (1x1, K=1024) + conv2 (3x3, K=2304) per (batch, pos-half).
// grid 256 = 128 b x 2 halves, 512 threads (8 waves, 2m x 4n).
// Phase 1: conv1 over 192 padded positions (half's 128 outputs + halo),
//          acc in regs; borders zeroed; -> bf16 swizzled LDS tile [192][256].
// Phase 2: conv2 36 (kq,kc) steps; B entirely from LDS (halo = row offset);
//          A2 reg-staged into single 32KB LDS buffer (T14 issue-early).
// LDS: 131072 dyn. Phase1: B0 dbuf 2x24K @0, A1 dbuf 2x32K @49152.
//       Phase2: xp1 [192][256] bf16 @0 (96K), A2 @98304 (32K).
// ---------------------------------------------------------------------------
__global__ __launch_bounds__(512, 2) void gemm12_conv(
    const u16* __restrict__ wb1, const u16* __restrict__ wb2,
    const u16* __restrict__ xp0, u16* __restrict__ xp2,
    const float* __restrict__ b1b, const float* __restrict__ b2a,
    const float* __restrict__ b2b, const float* __restrict__ b3a)
{
  extern __shared__ char lds[];
  const int t = threadIdx.x, lane = t & 63, w = t >> 6;
  const int wm  = (w >> 2) * 64;          // m within 128-pass
  const int wn1 = (w & 3) * 48;           // conv1 n (192 range)
  const int wn2 = (w & 3) * 32;           // conv2 n (128 range)
  const int b = blockIdx.x >> 1, half = blockIdx.x & 1;
  const int g0 = half*128 - 32;           // grid-pos of LDS row 0

  // ---------------- phase 1: conv1 ----------------
  uint32_t a1off[4], b0off[3];
  #pragma unroll
  for (int i = 0; i < 4; ++i){
    int gl = i*512 + t, row = gl >> 3, ss = gl & 7;
    a1off[i] = (uint32_t)row*2048 + ((ss ^ (row & 7)) << 4);
  }
  #pragma unroll
  for (int i = 0; i < 3; ++i){
    int gl = i*512 + t, row = gl >> 3, ss = gl & 7;
    int P = g0 + row, y = P >> 4, x = P & 15;
    bool valid = ((unsigned)P < 256u) && ((unsigned)(y-1) < 14u) && ((unsigned)(x-1) < 14u);
    int preal = valid ? (y-1)*14 + (x-1) : 0;
    b0off[i] = ((uint32_t)b*196 + preal)*2048 + ((ss ^ (row & 7)) << 4);
  }

  f32x4 acc1[2][4][3] = {};

  auto stage1 = [&](int buf, int s){
    char* B0 = lds + buf*24576;
    char* A1 = lds + 49152 + buf*32768;
    #pragma unroll
    for (int i = 0; i < 4; ++i)
      gl_lds16((const char*)wb1 + a1off[i] + s*128, A1 + (i*512 + t)*16);
    #pragma unroll
    for (int i = 0; i < 3; ++i)
      gl_lds16((const char*)xp0 + b0off[i] + s*128, B0 + (i*512 + t)*16);
  };
  auto compute1 = [&](int buf){
    char* B0 = lds + buf*24576;
    char* A1 = lds + 49152 + buf*32768;
    #pragma unroll
    for (int h = 0; h < 2; ++h){
      bf16x8 af[2][4], bf[3];
      #pragma unroll
      for (int p = 0; p < 2; ++p)
        #pragma unroll
        for (int i = 0; i < 4; ++i){
          int row = p*128 + wm + i*16 + (lane & 15);
          af[p][i] = *(const bf16x8*)(A1 + row*128 + (((h*4 + (lane>>4)) ^ (row & 7)) << 4));
        }
      #pragma unroll
      for (int j = 0; j < 3; ++j){
        int row = wn1 + j*16 + (lane & 15);
        bf[j] = *(const bf16x8*)(B0 + row*128 + (((h*4 + (lane>>4)) ^ (row & 7)) << 4));
      }
      #pragma unroll
      for (int p = 0; p < 2; ++p)
        #pragma unroll
        for (int i = 0; i < 4; ++i)
          #pragma unroll
          for (int j = 0; j < 3; ++j)
            acc1[p][i][j] = __builtin_amdgcn_mfma_f32_16x16x32_bf16(af[p][i], bf[j], acc1[p][i][j], 0, 0, 0);
    }
  };

  stage1(0, 0);
  __syncthreads();
  for (int s = 0; s < 16; ++s){
    if (s < 15) stage1((s+1) & 1, s+1);
    compute1(s & 1);
    __syncthreads();
  }

  // phase boundary: acc1 (+b1b+b2a, borders->0) -> xp1 LDS [192][256] bf16, swizzled
  {
    float badd1 = b1b[0] + b2a[0];
    #pragma unroll
    for (int p = 0; p < 2; ++p)
      #pragma unroll
      for (int i = 0; i < 4; ++i){
        int o = p*128 + wm + i*16 + ((lane >> 4) << 2);   // channel base (mult of 4)
        int go = o >> 3;
        #pragma unroll
        for (int j = 0; j < 3; ++j){
          int ni = wn1 + j*16 + (lane & 15);
          int P = g0 + ni, y = P >> 4, x = P & 15;
          bool valid = ((unsigned)P < 256u) && ((unsigned)(y-1) < 14u) && ((unsigned)(x-1) < 14u);
          ushort4 pk;
          #pragma unroll
          for (int q = 0; q < 4; ++q)
            ((u16*)&pk)[q] = valid ? f2bf(acc1[p][i][j][q] + badd1) : (u16)0;
          int gs = (go & 24) | ((go & 7) ^ (ni & 7));
          *(ushort4*)(lds + ni*512 + (gs << 4) + (o & 7)*2) = pk;
        }
      }
  }
  __syncthreads();

  // ---------------- phase 2: conv2 ----------------
  char* A2 = lds + 98304;
  uint32_t a2base[4];
  #pragma unroll
  for (int r = 0; r < 4; ++r){
    int gl = r*512 + t, row = gl >> 3, ss = gl & 7;
    a2base[r] = (uint32_t)row*4608 + ((ss ^ (row & 7)) << 4);
  }
  uint4 ar[4];
  auto loadA2 = [&](int kq, int kc){
    uint32_t off = (uint32_t)kq*512 + (uint32_t)kc*128;
    #pragma unroll
    for (int r = 0; r < 4; ++r)
      ar[r] = *(const uint4*)((const char*)wb2 + a2base[r] + off);
  };
  auto writeA2 = [&](){
    #pragma unroll
    for (int r = 0; r < 4; ++r)
      *(uint4*)(A2 + (r*512 + t)*16) = ar[r];
  };

  f32x4 acc2[2][4][2] = {};

  loadA2(0, 0);
  writeA2();
  __syncthreads();

  #pragma unroll
  for (int kq = 0; kq < 9; ++kq){
    const int dy = kq/3 - 1, dx = kq%3 - 1;
    const int shift = dy*16 + dx;
    #pragma unroll
    for (int kc = 0; kc < 4; ++kc){
      // issue next A2 tile loads early
      bool more = !(kq == 8 && kc == 3);
      if (more){
        int nkq = (kc == 3) ? kq + 1 : kq;
        int nkc = (kc == 3) ? 0 : kc + 1;
        loadA2(nkq, nkc);
      }
      // compute this step from A2 LDS + xp1 LDS
      #pragma unroll
      for (int h = 0; h < 2; ++h){
        bf16x8 af[2][4], bf[2];
        #pragma unroll
        for (int p = 0; p < 2; ++p)
          #pragma unroll
          for (int i = 0; i < 4; ++i){
            int row = p*128 + wm + i*16 + (lane & 15);
            af[p][i] = *(const bf16x8*)(A2 + row*128 + (((h*4 + (lane>>4)) ^ (row & 7)) << 4));
          }
        #pragma unroll
        for (int j = 0; j < 2; ++j){
          int row = 32 + wn2 + j*16 + (lane & 15) + shift;
          int gk = kc*8 + h*4 + (lane >> 4);
          int gs = (gk & 24) | ((gk & 7) ^ (row & 7));
          bf[j] = *(const bf16x8*)(lds + row*512 + (gs << 4));
        }
        #pragma unroll
        for (int p = 0; p < 2; ++p)
          #pragma unroll
          for (int i = 0; i < 4; ++i)
            #pragma unroll
            for (int j = 0; j < 2; ++j)
              acc2[p][i][j] = __builtin_amdgcn_mfma_f32_16x16x32_bf16(af[p][i], bf[j], acc2[p][i][j], 0, 0, 0);
      }
      __syncthreads();                 // all reads of A2 buffer done
      if (more) writeA2();             // (compiler waits vmcnt for ar)
      __syncthreads();                 // writes visible
    }
  }

  // epilogue: xp2[b*196+p][256] = acc2 + (b2b + b3a)
  {
    float badd2 = b2b[0] + b3a[0];
    #pragma unroll
    for (int p = 0; p < 2; ++p)
      #pragma unroll
      for (int i = 0; i < 4; ++i){
        int o = p*128 + wm + i*16 + ((lane >> 4) << 2);
        #pragma unroll
        for (int j = 0; j < 2; ++j){
          int no = wn2 + j*16 + (lane & 15);
          int P = half*128 + no, y = P >> 4, x = P & 15;
          if (((unsigned)(y-1) < 14u) && ((unsigned)(x-1) < 14u)){
            int preal = (y-1)*14 + (x-1);
            ushort4 pk;
            #pragma unroll
            for (int q = 0; q < 4; ++q) ((u16*)&pk)[q] = f2bf(acc2[p][i][j][q] + badd2);
            *(ushort4*)(xp2 + ((size_t)b*196 + preal)*256 + o) = pk;
          }
        }
      }
  }
}

// ---------------------------------------------------------------------------
// conv3 1x1 + scale/bias/residual-ReLU (unchanged round-5 structure)
// ---------------------------------------------------------------------------
__global__ __launch_bounds__(256, 4) void gemm3_conv(
    const u16* __restrict__ A, const u16* __restrict__ B, const u16* __restrict__ xresb,
    float* __restrict__ Of32, const float* __restrict__ s0, const float* __restrict__ s1,
    const float* __restrict__ s2){
  __shared__ char lds[33792];
  const int t = threadIdx.x, lane = t & 63, w = t >> 6;
  const int wm = (w >> 1) * 64, wn = (w & 1) * 64;
  const int orig = blockIdx.x;
  const int bid  = (orig & 7) * ((int)gridDim.x >> 3) + (orig >> 3);
  const int n0 = (bid >> 3) * 128, m0 = (bid & 7) * 128;
  f32x4 acc[4][4] = {};

  uint32_t aoff[4], boff[4];
  #pragma unroll
  for (int i = 0; i < 4; ++i){
    int gl = i*256 + t, row = gl >> 3, ss = gl & 7;
    int xo = (ss ^ (row & 7)) << 4;
    aoff[i] = (uint32_t)(m0 + row)*512 + xo;
    boff[i] = (uint32_t)(n0 + row)*512 + xo;
  }

  auto stage = [&](int s){
    char* Ab = lds;
    char* Bb = lds + 16384;
    #pragma unroll
    for (int i = 0; i < 4; ++i){
      gl_lds16((const char*)A + aoff[i] + s*128, Ab + (i*256 + t)*16);
      gl_lds16((const char*)B + boff[i] + s*128, Bb + (i*256 + t)*16);
    }
  };
  auto compute = [&](){
    char* Ab = lds;
    char* Bb = lds + 16384;
    #pragma unroll
    for (int h = 0; h < 2; ++h){
      bf16x8 af[4], bfr[4];
      #pragma unroll
      for (int i = 0; i < 4; ++i){
        int row = wm + i*16 + (lane & 15);
        af[i] = *(const bf16x8*)(Ab + row*128 + (((h*4 + (lane>>4)) ^ (row & 7)) << 4));
      }
      #pragma unroll
      for (int j = 0; j < 4; ++j){
        int row = wn + j*16 + (lane & 15);
        bfr[j] = *(const bf16x8*)(Bb + row*128 + (((h*4 + (lane>>4)) ^ (row & 7)) << 4));
      }
      #pragma unroll
      for (int i = 0; i < 4; ++i)
        #pragma unroll
        for (int j = 0; j < 4; ++j)
          acc[i][j] = __builtin_amdgcn_mfma_f32_16x16x32_bf16(af[i], bfr[j], acc[i][j], 0, 0, 0);
    }
  };

  #pragma unroll
  for (int s = 0; s < 4; ++s){
    if (s) __syncthreads();
    stage(s);
    __syncthreads();
    compute();
  }

  float b3 = s0[0], rs = s1[0], rbv = s2[0];
  float* ldsF = (float*)lds;                 // [64][132] padded f32 tile
  #pragma unroll
  for (int pass = 0; pass < 2; ++pass){
    __syncthreads();
    if ((wm >> 6) == pass){
      #pragma unroll
      for (int i = 0; i < 4; ++i){
        int rb = i*16 + ((lane >> 4) << 2);
        #pragma unroll
        for (int j = 0; j < 4; ++j){
          int col = wn + j*16 + (lane & 15);
          #pragma unroll
          for (int q = 0; q < 4; ++q) ldsF[(rb + q)*132 + col] = acc[i][j][q];
        }
      }
    }
    __syncthreads();
    #pragma unroll
    for (int r = 0; r < 8; ++r){
      int row = (w << 4) + ((lane >> 5) << 3) + r;     // 0..63
      int n4  = (lane & 31) << 2;
      float4 v = *(float4*)&ldsF[row*132 + n4];
      uint32_t n = n0 + n4;
      uint32_t b = n / 196u, p = n - b*196u;           // 196 % 4 == 0: no straddle
      int o = m0 + pass*64 + row;
      size_t base = ((size_t)b*1024 + o)*196 + p;
      const u16* xr = xresb + (size_t)n*1024 + o;      // bf16 residual [n][o]
      float4 ov;
      ov.x = fmaxf((v.x + b3)*rs + rbv + bf2f(xr[0]),    0.f);
      ov.y = fmaxf((v.y + b3)*rs + rbv + bf2f(xr[1024]), 0.f);
      ov.z = fmaxf((v.z + b3)*rs + rbv + bf2f(xr[2048]), 0.f);
      ov.w = fmaxf((v.w + b3)*rs + rbv + bf2f(xr[3072]), 0.f);
      *(float4*)&Of32[base] = ov;
    }
  }
}

// ---------------------------------------------------------------------------
extern "C" void kernel_launch(void* const* d_in, const int* in_sizes, int n_in,
                              void* d_out, int out_size, void* d_ws, size_t ws_size,
                              hipStream_t stream){
  (void)in_sizes; (void)n_in; (void)out_size; (void)ws_size;
  const float* x   = (const float*)d_in[0];
  const float* w1  = (const float*)d_in[1];
  const float* w2  = (const float*)d_in[2];
  const float* w3  = (const float*)d_in[3];
  const float* b1b = (const float*)d_in[4];
  const float* b2a = (const float*)d_in[5];
  const float* b2b = (const float*)d_in[6];
  const float* b3a = (const float*)d_in[7];
  const float* b3b = (const float*)d_in[8];
  const float* rsc = (const float*)d_in[9];
  const float* rbi = (const float*)d_in[10];

  // ws layout (bytes):
  //   (unused)  @ 0         : 16,777,216
  //   xp2       @ 16777216  : [25088][256] bf16 = 12,845,056
  //   xp0       @ 29622272  : [25088][1024] bf16 = 51,380,224
  //   wb1 @ 81002496 : 524,288 | wb2 @ 81526784 : 1,179,648 | wb3 @ 82706432 : 524,288
  char* ws  = (char*)d_ws;
  u16*  xp2 = (u16*)(ws + 16777216);
  u16*  xp0 = (u16*)(ws + 29622272);
  u16*  wb1 = (u16*)(ws + 81002496);
  u16*  wb2 = (u16*)(ws + 81526784);
  u16*  wb3 = (u16*)(ws + 82706432);

  prep_w     <<<dim3(4352),   256, 0, stream>>>(w1, w2, w3, wb1, wb2, wb3);
  transform_x<<<dim3(16,128), 256, 0, stream>>>(x, xp0);

  gemm12_conv<<<dim3(256),  512, 131072, stream>>>(wb1, wb2, xp0, xp2, b1b, b2a, b2b, b3a);
  gemm3_conv <<<dim3(1568), 256,      0, stream>>>(wb3, xp2, xp0, (float*)d_out, b3b, rsc, rbi);
}

// Round 8
// 324.054 us; speedup vs baseline: 1.2174x; 1.2174x over previous
//
#include <hip/hip_runtime.h>
#include <stdint.h>

typedef __bf16 bf16x8 __attribute__((ext_vector_type(8)));
typedef float f32x4 __attribute__((ext_vector_type(4)));
typedef unsigned short u16;

__device__ __forceinline__ u16 f2bf(float f){
  uint32_t u = __float_as_uint(f);
  u = (u + 0x7fffu + ((u >> 16) & 1u)) >> 16;
  return (u16)u;
}
__device__ __forceinline__ void gl_lds16(const void* g, void* l){
  __builtin_amdgcn_global_load_lds((const __attribute__((address_space(1))) void*)g,
                                   (__attribute__((address_space(3))) void*)l, 16, 0, 0);
}

// ---------------------------------------------------------------------------
// Merged prep: w1/w3 cvt, w2 repack [O][kq][C], and x NCHW->NHWC bf16 transform
// blocks: [0,1024) w1 | [1024,3328) w2 | [3328,4352) w3 | [4352,6400) transform
// ---------------------------------------------------------------------------
__global__ __launch_bounds__(256) void prep_transform(
    const float* __restrict__ w1, const float* __restrict__ w2,
    const float* __restrict__ w3, const float* __restrict__ x,
    u16* __restrict__ wb1, u16* __restrict__ wb2, u16* __restrict__ wb3,
    u16* __restrict__ xp0){
  __shared__ float lds[64*201];
  int bid = blockIdx.x, t = threadIdx.x;
  if (bid < 1024){
    int i = bid*256 + t; wb1[i] = f2bf(w1[i]);
  } else if (bid < 3328){
    int i = (bid-1024)*256 + t;
    int o = i / 2304, r = i - o*2304, kq = r >> 8, c = r & 255;
    wb2[i] = f2bf(w2[((size_t)o*256 + c)*9 + kq]);
  } else if (bid < 4352){
    int i = (bid-3328)*256 + t; wb3[i] = f2bf(w3[i]);
  } else {
    int lin = bid - 4352;                 // 0..2047
    int b = lin >> 4, c0 = (lin & 15)*64;
    const float4* src = (const float4*)x + (size_t)b*50176 + (size_t)c0*49;
    #pragma unroll
    for (int r = 0; r < 13; ++r){
      int q = r*256 + t;                  // 3136 float4 = 64ch x 49
      if (q < 3136){
        unsigned c = (unsigned)q / 49u, f = (unsigned)q - c*49u;
        float4 v = src[q];
        float* d = &lds[c*201 + f*4];
        d[0]=v.x; d[1]=v.y; d[2]=v.z; d[3]=v.w;
      }
    }
    __syncthreads();
    const int c4 = (t & 15)*4, pg = t >> 4;
    #pragma unroll
    for (int r = 0; r < 13; ++r){
      int p = r*16 + pg;
      if (p < 196){
        ushort4 pk;
        ((u16*)&pk)[0] = f2bf(lds[(c4+0)*201 + p]);
        ((u16*)&pk)[1] = f2bf(lds[(c4+1)*201 + p]);
        ((u16*)&pk)[2] = f2bf(lds[(c4+2)*201 + p]);
        ((u16*)&pk)[3] = f2bf(lds[(c4+3)*201 + p]);
        *(ushort4*)&xp0[((size_t)b*196 + p)*1024 + c0 + c4] = pk;
      }
    }
  }
}

// ---------------------------------------------------------------------------
// conv1 1x1: per (batch, m-half). grid 256, 512 thr (8 waves, 2m x 4n).
// BK=32 double-buffered: LDS = B 2x16K + A 2x8K = 48K -> 2 blocks/CU.
// Output xp1 [b][256 gridpos][256 ch], borders written as literal zeros.
// ---------------------------------------------------------------------------
__global__ __launch_bounds__(512, 4) void gemm1_conv(
    const u16* __restrict__ A, const u16* __restrict__ B, u16* __restrict__ O,
    const float* __restrict__ s0, const float* __restrict__ s1){
  __shared__ char lds[49152];
  const int t = threadIdx.x, lane = t & 63, w = t >> 6;
  const int wm = (w >> 2) * 64, wn = (w & 3) * 64;
  const int b = blockIdx.x >> 1, m0 = (blockIdx.x & 1) * 128;
  f32x4 acc[4][4] = {};

  uint32_t aoff, boff[2];
  { int row = t >> 2, ss = t & 3;
    aoff = (uint32_t)(m0 + row)*2048 + ((ss ^ (row & 3)) << 4); }
  #pragma unroll
  for (int i = 0; i < 2; ++i){
    int gl = i*512 + t, row = gl >> 2, ss = gl & 3;  // row = grid pos 0..255
    int y = row >> 4, xx = row & 15;
    int p = ((unsigned)(y-1) < 14u && (unsigned)(xx-1) < 14u) ? (y-1)*14 + (xx-1) : 0;
    boff[i] = ((uint32_t)b*196 + p)*2048 + ((ss ^ (row & 3)) << 4);
  }

  auto stage = [&](int buf, int s){
    char* Bb = lds + buf*16384;
    char* Ab = lds + 32768 + buf*8192;
    gl_lds16((const char*)A + aoff + s*64, Ab + t*16);
    #pragma unroll
    for (int i = 0; i < 2; ++i)
      gl_lds16((const char*)B + boff[i] + s*64, Bb + (i*512 + t)*16);
  };
  auto compute = [&](int buf){
    char* Bb = lds + buf*16384;
    char* Ab = lds + 32768 + buf*8192;
    bf16x8 af[4], bfr[4];
    #pragma unroll
    for (int i = 0; i < 4; ++i){
      int row = wm + i*16 + (lane & 15);
      af[i] = *(const bf16x8*)(Ab + row*64 + (((lane>>4) ^ (row & 3)) << 4));
    }
    #pragma unroll
    for (int j = 0; j < 4; ++j){
      int row = wn + j*16 + (lane & 15);
      bfr[j] = *(const bf16x8*)(Bb + row*64 + (((lane>>4) ^ (row & 3)) << 4));
    }
    #pragma unroll
    for (int i = 0; i < 4; ++i)
      #pragma unroll
      for (int j = 0; j < 4; ++j)
        acc[i][j] = __builtin_amdgcn_mfma_f32_16x16x32_bf16(af[i], bfr[j], acc[i][j], 0, 0, 0);
  };

  stage(0, 0);
  __syncthreads();
  for (int s = 0; s < 32; ++s){
    if (s < 31) stage((s+1) & 1, s+1);
    compute(s & 1);
    __syncthreads();
  }

  float badd = s0[0] + s1[0];
  #pragma unroll
  for (int i = 0; i < 4; ++i){
    int o = m0 + wm + i*16 + ((lane >> 4) << 2);
    #pragma unroll
    for (int j = 0; j < 4; ++j){
      int n = wn + j*16 + (lane & 15);
      int y = n >> 4, xx = n & 15;
      bool real = ((unsigned)(y-1) < 14u) && ((unsigned)(xx-1) < 14u);
      ushort4 pk;
      #pragma unroll
      for (int q = 0; q < 4; ++q)
        ((u16*)&pk)[q] = real ? f2bf(acc[i][j][q] + badd) : (u16)0;
      *(ushort4*)(O + ((size_t)b*256 + n)*256 + o) = pk;
    }
  }
}

// ---------------------------------------------------------------------------
// conv2 3x3: per (batch, m-half). grid 256, 512 thr (8 waves, 2m x 4n).
// B = batch's padded grid + 18-row guards, SINGLE buffer staged once per kc;
// 9 kq shifts = LDS row offsets. A double-buffered per (kq,kc).
// LDS: A dbuf 2x16K @0, B 37376 @32768 -> 70144 -> 2 blocks/CU.
// ---------------------------------------------------------------------------
__global__ __launch_bounds__(512, 4) void gemm2_conv(
    const u16* __restrict__ A, const u16* __restrict__ B, u16* __restrict__ O,
    const float* __restrict__ s0, const float* __restrict__ s1){
  extern __shared__ char lds[];
  const int t = threadIdx.x, lane = t & 63, w = t >> 6;
  const int wm = (w >> 2) * 64, wn = (w & 3) * 64;
  const int b = blockIdx.x >> 1, m0 = (blockIdx.x & 1) * 128;
  f32x4 acc[4][4] = {};

  uint32_t aoff[2], boff[5];
  #pragma unroll
  for (int i = 0; i < 2; ++i){
    int gl = i*512 + t, row = gl >> 3, ss = gl & 7;
    aoff[i] = (uint32_t)(m0 + row)*4608 + ((ss ^ (row & 7)) << 4);
  }
  #pragma unroll
  for (int i = 0; i < 5; ++i){
    int gl = i*512 + t, row = gl >> 3, ss = gl & 7;   // LDS row 0..291
    int pos = row - 18;
    pos = pos < 0 ? 0 : (pos > 255 ? 255 : pos);      // clamped guards (zeros/borders)
    boff[i] = ((uint32_t)b*256 + pos)*512 + ((ss ^ (row & 7)) << 4);
  }

  auto stageA = [&](int buf, int kq, int kc){
    char* Ab = lds + buf*16384;
    int off = kq*512 + kc*128;
    #pragma unroll
    for (int i = 0; i < 2; ++i)
      gl_lds16((const char*)A + aoff[i] + off, Ab + (i*512 + t)*16);
  };
  auto stageB = [&](int kc){
    char* Bb = lds + 32768;
    #pragma unroll
    for (int i = 0; i < 5; ++i){
      int gl = i*512 + t;
      if (gl < 2336) gl_lds16((const char*)B + boff[i] + kc*128, Bb + gl*16);
    }
  };
  auto compute = [&](int ab, int shift){
    char* Ab = lds + ab*16384;
    char* Bb = lds + 32768;
    #pragma unroll
    for (int h = 0; h < 2; ++h){
      bf16x8 af[4], bfr[4];
      #pragma unroll
      for (int i = 0; i < 4; ++i){
        int row = wm + i*16 + (lane & 15);
        af[i] = *(const bf16x8*)(Ab + row*128 + (((h*4 + (lane>>4)) ^ (row & 7)) << 4));
      }
      #pragma unroll
      for (int j = 0; j < 4; ++j){
        int row = 18 + wn + j*16 + (lane & 15) + shift;
        bfr[j] = *(const bf16x8*)(Bb + row*128 + (((h*4 + (lane>>4)) ^ (row & 7)) << 4));
      }
      #pragma unroll
      for (int i = 0; i < 4; ++i)
        #pragma unroll
        for (int j = 0; j < 4; ++j)
          acc[i][j] = __builtin_amdgcn_mfma_f32_16x16x32_bf16(af[i], bfr[j], acc[i][j], 0, 0, 0);
    }
  };

  int cur = 0;
  stageB(0); stageA(cur, 0, 0);
  __syncthreads();
  #pragma unroll
  for (int kc = 0; kc < 4; ++kc){
    #pragma unroll
    for (int kq = 0; kq < 9; ++kq){
      if (kq < 8) stageA(cur ^ 1, kq + 1, kc);
      compute(cur, (kq/3 - 1)*16 + (kq%3) - 1);
      __syncthreads();
      if (kq < 8) cur ^= 1;
    }
    if (kc < 3){
      stageB(kc + 1); stageA(cur ^ 1, 0, kc + 1);
      __syncthreads();
      cur ^= 1;
    }
  }

  float badd = s0[0] + s1[0];
  #pragma unroll
  for (int i = 0; i < 4; ++i){
    int o = m0 + wm + i*16 + ((lane >> 4) << 2);
    #pragma unroll
    for (int j = 0; j < 4; ++j){
      int n = wn + j*16 + (lane & 15);
      int y = n >> 4, xx = n & 15;
      if (((unsigned)(y-1) < 14u) && ((unsigned)(xx-1) < 14u)){
        int p = (y-1)*14 + (xx-1);
        ushort4 pk;
        #pragma unroll
        for (int q = 0; q < 4; ++q) ((u16*)&pk)[q] = f2bf(acc[i][j][q] + badd);
        *(ushort4*)(O + ((size_t)b*196 + p)*256 + o) = pk;
      }
    }
  }
}

// ---------------------------------------------------------------------------
// conv3 1x1 + scale/bias/residual-ReLU. BM=128 BN=128 single-buf;
// LDS-transposed f32 epilogue; COALESCED f32 x residual (shares store base).
// m-fastest + XCD chunk swizzle. 4 blocks/CU.
// ---------------------------------------------------------------------------
__global__ __launch_bounds__(256, 4) void gemm3_conv(
    const u16* __restrict__ A, const u16* __restrict__ B, const float* __restrict__ xres,
    float* __restrict__ Of32, const float* __restrict__ s0, const float* __restrict__ s1,
    const float* __restrict__ s2){
  __shared__ char lds[33792];
  const int t = threadIdx.x, lane = t & 63, w = t >> 6;
  const int wm = (w >> 1) * 64, wn = (w & 1) * 64;
  const int orig = blockIdx.x;
  const int bid  = (orig & 7) * ((int)gridDim.x >> 3) + (orig >> 3);
  const int n0 = (bid >> 3) * 128, m0 = (bid & 7) * 128;
  f32x4 acc[4][4] = {};

  uint32_t aoff[4], boff[4];
  #pragma unroll
  for (int i = 0; i < 4; ++i){
    int gl = i*256 + t, row = gl >> 3, ss = gl & 7;
    int xo = (ss ^ (row & 7)) << 4;
    aoff[i] = (uint32_t)(m0 + row)*512 + xo;
    boff[i] = (uint32_t)(n0 + row)*512 + xo;
  }

  auto stage = [&](int s){
    char* Ab = lds;
    char* Bb = lds + 16384;
    #pragma unroll
    for (int i = 0; i < 4; ++i){
      gl_lds16((const char*)A + aoff[i] + s*128, Ab + (i*256 + t)*16);
      gl_lds16((const char*)B + boff[i] + s*128, Bb + (i*256 + t)*16);
    }
  };
  auto compute = [&](){
    char* Ab = lds;
    char* Bb = lds + 16384;
    #pragma unroll
    for (int h = 0; h < 2; ++h){
      bf16x8 af[4], bfr[4];
      #pragma unroll
      for (int i = 0; i < 4; ++i){
        int row = wm + i*16 + (lane & 15);
        af[i] = *(const bf16x8*)(Ab + row*128 + (((h*4 + (lane>>4)) ^ (row & 7)) << 4));
      }
      #pragma unroll
      for (int j = 0; j < 4; ++j){
        int row = wn + j*16 + (lane & 15);
        bfr[j] = *(const bf16x8*)(Bb + row*128 + (((h*4 + (lane>>4)) ^ (row & 7)) << 4));
      }
      #pragma unroll
      for (int i = 0; i < 4; ++i)
        #pragma unroll
        for (int j = 0; j < 4; ++j)
          acc[i][j] = __builtin_amdgcn_mfma_f32_16x16x32_bf16(af[i], bfr[j], acc[i][j], 0, 0, 0);
    }
  };

  #pragma unroll
  for (int s = 0; s < 4; ++s){
    if (s) __syncthreads();
    stage(s);
    __syncthreads();
    compute();
  }

  float b3 = s0[0], rs = s1[0], rbv = s2[0];
  float* ldsF = (float*)lds;                 // [64][132] padded f32 tile
  #pragma unroll
  for (int pass = 0; pass < 2; ++pass){
    __syncthreads();
    if ((wm >> 6) == pass){
      #pragma unroll
      for (int i = 0; i < 4; ++i){
        int rb = i*16 + ((lane >> 4) << 2);
        #pragma unroll
        for (int j = 0; j < 4; ++j){
          int col = wn + j*16 + (lane & 15);
          #pragma unroll
          for (int q = 0; q < 4; ++q) ldsF[(rb + q)*132 + col] = acc[i][j][q];
        }
      }
    }
    __syncthreads();
    #pragma unroll
    for (int r = 0; r < 8; ++r){
      int row = (w << 4) + ((lane >> 5) << 3) + r;     // 0..63
      int n4  = (lane & 31) << 2;
      float4 v = *(float4*)&ldsF[row*132 + n4];
      uint32_t n = n0 + n4;
      uint32_t b = n / 196u, p = n - b*196u;           // 196 % 4 == 0: no straddle
      int o = m0 + pass*64 + row;
      size_t base = ((size_t)b*1024 + o)*196 + p;
      float4 xr = *(const float4*)&xres[base];
      float4 ov;
      ov.x = fmaxf((v.x + b3)*rs + rbv + xr.x, 0.f);
      ov.y = fmaxf((v.y + b3)*rs + rbv + xr.y, 0.f);
      ov.z = fmaxf((v.z + b3)*rs + rbv + xr.z, 0.f);
      ov.w = fmaxf((v.w + b3)*rs + rbv + xr.w, 0.f);
      *(float4*)&Of32[base] = ov;
    }
  }
}

// ---------------------------------------------------------------------------
extern "C" void kernel_launch(void* const* d_in, const int* in_sizes, int n_in,
                              void* d_out, int out_size, void* d_ws, size_t ws_size,
                              hipStream_t stream){
  (void)in_sizes; (void)n_in; (void)out_size; (void)ws_size;
  const float* x   = (const float*)d_in[0];
  const float* w1  = (const float*)d_in[1];
  const float* w2  = (const float*)d_in[2];
  const float* w3  = (const float*)d_in[3];
  const float* b1b = (const float*)d_in[4];
  const float* b2a = (const float*)d_in[5];
  const float* b2b = (const float*)d_in[6];
  const float* b3a = (const float*)d_in[7];
  const float* b3b = (const float*)d_in[8];
  const float* rsc = (const float*)d_in[9];
  const float* rbi = (const float*)d_in[10];

  // ws layout (bytes):
  //   xp1 @ 0         : [128 b][256 gridpos][256 ch] bf16 = 16,777,216
  //   xp2 @ 16777216  : [25088][256] bf16                 = 12,845,056
  //   xp0 @ 29622272  : [25088][1024] bf16                = 51,380,224
  //   wb1 @ 81002496 : 524,288 | wb2 @ 81526784 : 1,179,648 | wb3 @ 82706432 : 524,288
  char* ws  = (char*)d_ws;
  u16*  xp1 = (u16*)ws;
  u16*  xp2 = (u16*)(ws + 16777216);
  u16*  xp0 = (u16*)(ws + 29622272);
  u16*  wb1 = (u16*)(ws + 81002496);
  u16*  wb2 = (u16*)(ws + 81526784);
  u16*  wb3 = (u16*)(ws + 82706432);

  prep_transform<<<dim3(6400), 256, 0, stream>>>(w1, w2, w3, x, wb1, wb2, wb3, xp0);

  gemm1_conv<<<dim3(256),  512,     0, stream>>>(wb1, xp0, xp1, b1b, b2a);
  gemm2_conv<<<dim3(256),  512, 70144, stream>>>(wb2, xp1, xp2, b2b, b3a);
  gemm3_conv<<<dim3(1568), 256,     0, stream>>>(wb3, xp2, x, (float*)d_out, b3b, rsc, rbi);
}